// Round 1
// baseline (311.461 us; speedup 1.0000x reference)
//
#include <hip/hip_runtime.h>
#include <float.h>

// CorrLoss: loss = mean(relu(max_neg(corr) - min_pos(corr) + 40))
// corr = feat @ feat^T, feat (4096,512) fp32, targets (4096,) int
//
// Kernel 1: fused tiled GEMM + masked per-row min/max, JSPLIT partials in ws.
// Kernel 2: fold partials -> loss scalar.

#define N_ROWS 4096
#define D_K    512
#define BM     64
#define BN     64
#define BK     32
#define JSPLIT 16
#define NJT    (N_ROWS / (JSPLIT * BN))   // j-tiles per block = 4
#define LDA    (BM + 4)                   // padded LDS leading dim (keeps 16B align)
#define MARGIN 40.0f

__global__ __launch_bounds__(256) void gram_minmax_kernel(
    const float* __restrict__ feat, const int* __restrict__ tgt,
    float* __restrict__ ap_part, float* __restrict__ an_part)
{
    __shared__ float As[BK][LDA];
    __shared__ float Bs[BK][LDA];
    __shared__ float red[BM][16];

    const int tid = threadIdx.x;
    const int tx  = tid & 15;        // 16 cols of threads
    const int ty  = tid >> 4;        // 16 rows of threads
    const int i0  = blockIdx.x * BM;
    const int js  = blockIdx.y;
    const int j0b = js * (N_ROWS / JSPLIT);

    // loader mapping: 256 threads stage 64x32 tile as 2 float4 each
    const int lkq = tid & 7;         // float4 index along K (0..7 -> k = lkq*4)
    const int lm  = tid >> 3;        // row within tile (0..31, +32 second pass)

    const int row0 = ty * 4;         // this thread's 4 contiguous rows in tile
    const int col0 = tx * 4;         // this thread's 4 contiguous cols in tile

    int ti[4];
#pragma unroll
    for (int r = 0; r < 4; ++r) ti[r] = tgt[i0 + row0 + r];

    float ap[4], an[4];
#pragma unroll
    for (int r = 0; r < 4; ++r) { ap[r] = FLT_MAX; an[r] = -FLT_MAX; }

    for (int jt = 0; jt < NJT; ++jt) {
        const int j0 = j0b + jt * BN;

        float c[4][4];
#pragma unroll
        for (int a = 0; a < 4; ++a)
#pragma unroll
            for (int b = 0; b < 4; ++b) c[a][b] = 0.0f;

        for (int k0 = 0; k0 < D_K; k0 += BK) {
            // stage A (rows) and B (cols) tiles, K-major transposed in LDS
#pragma unroll
            for (int p = 0; p < 2; ++p) {
                const int m = lm + p * 32;
                const float4 av = *(const float4*)&feat[(size_t)(i0 + m) * D_K + k0 + lkq * 4];
                const float4 bv = *(const float4*)&feat[(size_t)(j0 + m) * D_K + k0 + lkq * 4];
                As[lkq * 4 + 0][m] = av.x; As[lkq * 4 + 1][m] = av.y;
                As[lkq * 4 + 2][m] = av.z; As[lkq * 4 + 3][m] = av.w;
                Bs[lkq * 4 + 0][m] = bv.x; Bs[lkq * 4 + 1][m] = bv.y;
                Bs[lkq * 4 + 2][m] = bv.z; Bs[lkq * 4 + 3][m] = bv.w;
            }
            __syncthreads();

#pragma unroll
            for (int kk = 0; kk < BK; ++kk) {
                const float4 a4 = *(const float4*)&As[kk][row0];
                const float4 b4 = *(const float4*)&Bs[kk][col0];
                const float a[4] = {a4.x, a4.y, a4.z, a4.w};
                const float b[4] = {b4.x, b4.y, b4.z, b4.w};
#pragma unroll
                for (int aa = 0; aa < 4; ++aa)
#pragma unroll
                    for (int bb = 0; bb < 4; ++bb)
                        c[aa][bb] = fmaf(a[aa], b[bb], c[aa][bb]);
            }
            __syncthreads();
        }

        // masked min/max epilogue for this j-tile
#pragma unroll
        for (int bb = 0; bb < 4; ++bb) {
            const int tj = tgt[j0 + col0 + bb];
#pragma unroll
            for (int aa = 0; aa < 4; ++aa) {
                if (ti[aa] == tj) ap[aa] = fminf(ap[aa], c[aa][bb]);
                else              an[aa] = fmaxf(an[aa], c[aa][bb]);
            }
        }
    }

    // cross-tx reduce (16 partials per row) and write slice partials
#pragma unroll
    for (int r = 0; r < 4; ++r) red[row0 + r][tx] = ap[r];
    __syncthreads();
    if (tid < BM) {
        float v = red[tid][0];
#pragma unroll
        for (int t = 1; t < 16; ++t) v = fminf(v, red[tid][t]);
        ap_part[js * N_ROWS + i0 + tid] = v;
    }
    __syncthreads();
#pragma unroll
    for (int r = 0; r < 4; ++r) red[row0 + r][tx] = an[r];
    __syncthreads();
    if (tid < BM) {
        float v = red[tid][0];
#pragma unroll
        for (int t = 1; t < 16; ++t) v = fmaxf(v, red[tid][t]);
        an_part[js * N_ROWS + i0 + tid] = v;
    }
}

__global__ __launch_bounds__(1024) void loss_kernel(
    const float* __restrict__ ap_part, const float* __restrict__ an_part,
    float* __restrict__ out)
{
    __shared__ float sred[1024];
    const int tid = threadIdx.x;
    float local = 0.0f;
    for (int row = tid; row < N_ROWS; row += 1024) {
        float ap = FLT_MAX, an = -FLT_MAX;
#pragma unroll
        for (int js = 0; js < JSPLIT; ++js) {
            ap = fminf(ap, ap_part[js * N_ROWS + row]);
            an = fmaxf(an, an_part[js * N_ROWS + row]);
        }
        const float v = an - ap + MARGIN;
        local += (v > 0.0f) ? v : 0.0f;
    }
    sred[tid] = local;
    __syncthreads();
    for (int s = 512; s > 0; s >>= 1) {
        if (tid < s) sred[tid] += sred[tid + s];
        __syncthreads();
    }
    if (tid == 0) out[0] = sred[0] / (float)N_ROWS;
}

extern "C" void kernel_launch(void* const* d_in, const int* in_sizes, int n_in,
                              void* d_out, int out_size, void* d_ws, size_t ws_size,
                              hipStream_t stream)
{
    const float* feat = (const float*)d_in[0];
    const int*   tgt  = (const int*)d_in[1];

    float* ap_part = (float*)d_ws;                    // JSPLIT * N floats
    float* an_part = ap_part + (size_t)JSPLIT * N_ROWS;

    dim3 grid(N_ROWS / BM, JSPLIT);
    gram_minmax_kernel<<<grid, 256, 0, stream>>>(feat, tgt, ap_part, an_part);
    loss_kernel<<<1, 1024, 0, stream>>>(ap_part, an_part, (float*)d_out);
}

// Round 2
// 105.283 us; speedup vs baseline: 2.9583x; 2.9583x over previous
//
#include <hip/hip_runtime.h>
#include <float.h>
#include <stdint.h>

// CorrLoss via bf16 MFMA:
//   k0: cast feat fp32 -> bf16 (RNE) into ws
//   k1: 128x128-tile Gram GEMM (mfma_f32_16x16x32_bf16, global_load_lds w=16)
//       fused masked per-row min/max epilogue -> per-column-tile partials in ws
//   k2: fold 32 partials/row -> relu(an-ap+40) -> mean (atomicAdd, out memset 0)

#define N_ROWS 4096
#define D_K    512
#define BM     128
#define BN     128
#define BK     32
#define NJT    (N_ROWS / BN)     // 32 column tiles -> 32 partial slices
#define MARGIN 40.0f

typedef __bf16 bf16_t;
typedef bf16_t bf16x8 __attribute__((ext_vector_type(8)));
typedef float  floatx4 __attribute__((ext_vector_type(4)));
typedef unsigned short ushort_t;

#define GLOAD_LDS16(g, l)                                        \
    __builtin_amdgcn_global_load_lds(                            \
        (const __attribute__((address_space(1))) void*)(g),      \
        (__attribute__((address_space(3))) void*)(l), 16, 0, 0)

__device__ __forceinline__ ushort_t f2bf_rne(float x) {
    uint32_t u = __builtin_bit_cast(uint32_t, x);
    return (ushort_t)((u + 0x7FFFu + ((u >> 16) & 1u)) >> 16);
}

typedef ushort_t ushortx8 __attribute__((ext_vector_type(8)));

__global__ __launch_bounds__(256) void cast_kernel(
    const float* __restrict__ f, ushort_t* __restrict__ o)
{
    const int i = (blockIdx.x * 256 + threadIdx.x) * 8;
    const float4 v0 = *(const float4*)(f + i);
    const float4 v1 = *(const float4*)(f + i + 4);
    ushortx8 r;
    r[0] = f2bf_rne(v0.x); r[1] = f2bf_rne(v0.y);
    r[2] = f2bf_rne(v0.z); r[3] = f2bf_rne(v0.w);
    r[4] = f2bf_rne(v1.x); r[5] = f2bf_rne(v1.y);
    r[6] = f2bf_rne(v1.z); r[7] = f2bf_rne(v1.w);
    *(ushortx8*)(o + i) = r;
}

__global__ __launch_bounds__(256) void gram_mfma_kernel(
    const ushort_t* __restrict__ fb, const int* __restrict__ tgt,
    float* __restrict__ ap_part, float* __restrict__ an_part)
{
    // 8 KB each tile, row-major [row][k], row stride 32 bf16 = 64 B
    __shared__ __align__(16) ushort_t As[BM * BK];
    __shared__ __align__(16) ushort_t Bs[BN * BK];
    __shared__ int tgI[BM];
    __shared__ int tgJ[BN];
    __shared__ float apRed[2][BM];
    __shared__ float anRed[2][BM];

    const int tid  = threadIdx.x;
    const int i0   = blockIdx.y * BM;
    const int j0   = blockIdx.x * BN;
    const int lane = tid & 63;
    const int wave = tid >> 6;
    const int wr   = wave >> 1;      // wave row half (0/1)
    const int wc   = wave & 1;       // wave col half (0/1)
    const int lr   = lane & 15;      // lane row/col within 16-tile
    const int lg   = lane >> 4;      // lane k-group (0..3)

    if (tid < BM)            tgI[tid]       = tgt[i0 + tid];
    else if (tid < BM + BN)  tgJ[tid - BM]  = tgt[j0 + tid - BM];

    // staging map: thread t loads 16 B = 8 bf16 of row (t>>2), k-quad (t&3)
    const int srow = tid >> 2;
    const int skq  = tid & 3;
    const size_t gA0 = (size_t)(i0 + srow) * D_K + skq * 8;
    const size_t gB0 = (size_t)(j0 + srow) * D_K + skq * 8;
    char* AsB = (char*)As;
    char* BsB = (char*)Bs;

    floatx4 acc[4][4];
#pragma unroll
    for (int a = 0; a < 4; ++a)
#pragma unroll
        for (int b = 0; b < 4; ++b) acc[a][b] = (floatx4)0.0f;

    for (int k0 = 0; k0 < D_K; k0 += BK) {
        GLOAD_LDS16(fb + gA0 + k0,               AsB + tid * 16);
        GLOAD_LDS16(fb + gA0 + k0 + 64 * D_K,    AsB + 4096 + tid * 16);
        GLOAD_LDS16(fb + gB0 + k0,               BsB + tid * 16);
        GLOAD_LDS16(fb + gB0 + k0 + 64 * D_K,    BsB + 4096 + tid * 16);
        __syncthreads();

        bf16x8 af[4], bf[4];
#pragma unroll
        for (int rg = 0; rg < 4; ++rg)
            af[rg] = *(const bf16x8*)(As + ((wr * 64 + rg * 16 + lr) * BK + lg * 8));
#pragma unroll
        for (int cg = 0; cg < 4; ++cg)
            bf[cg] = *(const bf16x8*)(Bs + ((wc * 64 + cg * 16 + lr) * BK + lg * 8));
#pragma unroll
        for (int rg = 0; rg < 4; ++rg)
#pragma unroll
            for (int cg = 0; cg < 4; ++cg)
                acc[rg][cg] = __builtin_amdgcn_mfma_f32_16x16x32_bf16(
                    af[rg], bf[cg], acc[rg][cg], 0, 0, 0);
        __syncthreads();
    }

    // epilogue: C/D layout col = lane&15, row = (lane>>4)*4 + reg
    int tj[4];
#pragma unroll
    for (int cg = 0; cg < 4; ++cg) tj[cg] = tgJ[wc * 64 + cg * 16 + lr];

#pragma unroll
    for (int rg = 0; rg < 4; ++rg) {
#pragma unroll
        for (int r = 0; r < 4; ++r) {
            const int rloc = wr * 64 + rg * 16 + lg * 4 + r;
            const int ti = tgI[rloc];
            float vap = FLT_MAX, van = -FLT_MAX;
#pragma unroll
            for (int cg = 0; cg < 4; ++cg) {
                const float v = acc[rg][cg][r];
                if (ti == tj[cg]) vap = fminf(vap, v);
                else              van = fmaxf(van, v);
            }
            // reduce across the 16 lanes (lr = 0..15) sharing this row
#pragma unroll
            for (int m = 1; m < 16; m <<= 1) {
                vap = fminf(vap, __shfl_xor(vap, m));
                van = fmaxf(van, __shfl_xor(van, m));
            }
            if (lr == 0) { apRed[wc][rloc] = vap; anRed[wc][rloc] = van; }
        }
    }
    __syncthreads();

    if (tid < BM) {
        ap_part[(size_t)blockIdx.x * N_ROWS + i0 + tid] =
            fminf(apRed[0][tid], apRed[1][tid]);
        an_part[(size_t)blockIdx.x * N_ROWS + i0 + tid] =
            fmaxf(anRed[0][tid], anRed[1][tid]);
    }
}

__global__ __launch_bounds__(256) void fold_kernel(
    const float* __restrict__ ap_part, const float* __restrict__ an_part,
    float* __restrict__ out)
{
    __shared__ float sred[4];
    const int tid = threadIdx.x;
    const int row = blockIdx.x * 256 + tid;
    float ap = FLT_MAX, an = -FLT_MAX;
#pragma unroll
    for (int js = 0; js < NJT; ++js) {
        ap = fminf(ap, ap_part[(size_t)js * N_ROWS + row]);
        an = fmaxf(an, an_part[(size_t)js * N_ROWS + row]);
    }
    const float v = an - ap + MARGIN;
    float s = (v > 0.0f) ? v : 0.0f;
#pragma unroll
    for (int m = 32; m >= 1; m >>= 1) s += __shfl_down(s, m);
    if ((tid & 63) == 0) sred[tid >> 6] = s;
    __syncthreads();
    if (tid == 0)
        atomicAdd(out, (sred[0] + sred[1] + sred[2] + sred[3]) * (1.0f / N_ROWS));
}

extern "C" void kernel_launch(void* const* d_in, const int* in_sizes, int n_in,
                              void* d_out, int out_size, void* d_ws, size_t ws_size,
                              hipStream_t stream)
{
    const float* feat = (const float*)d_in[0];
    const int*   tgt  = (const int*)d_in[1];

    ushort_t* fb      = (ushort_t*)d_ws;                       // 4 MB bf16 feat
    float*    ap_part = (float*)(fb + (size_t)N_ROWS * D_K);   // 32*4096 floats
    float*    an_part = ap_part + (size_t)NJT * N_ROWS;        // 32*4096 floats

    cast_kernel<<<(N_ROWS * D_K) / (256 * 8), 256, 0, stream>>>(feat, fb);

    dim3 grid(N_ROWS / BN, N_ROWS / BM);
    gram_mfma_kernel<<<grid, 256, 0, stream>>>(fb, tgt, ap_part, an_part);

    hipMemsetAsync(d_out, 0, sizeof(float), stream);
    fold_kernel<<<N_ROWS / 256, 256, 0, stream>>>(ap_part, an_part, (float*)d_out);
}